// Round 17
// baseline (557.954 us; speedup 1.0000x reference)
//
#include <hip/hip_runtime.h>

#define OBS 8
#define PREDL 12
#define NCELL 19   // cell evals t=0..18; x_t=head(h_{t-1}) for t>=8; emit p=t-8; p=11 in tail

// LDS map (bytes) — exactly 160 KiB
#define W_OFF    0        // 98304: W_hh i,f,g interleaved (col*3+gate)*256, swizzled(&15), prescaled
#define H0_OFF   98304    // 16384: h group0 (single buffer; 2-phase barrier discipline)
#define H1_OFF   114688   // 16384: h group1
#define RH0_OFF  131072   // 16384: relu(h) group0
#define RH1_OFF  147456   // 16384: relu(h) group1
#define LDS_BYTES 163840

typedef short short8 __attribute__((ext_vector_type(8)));
typedef float f32x16 __attribute__((ext_vector_type(16)));
struct U128 { unsigned a, b, c, d; };

#define NL2E  (-1.4426950408889634f)   // -log2(e)
#define N2L2E (-2.8853900817779268f)   // -2*log2(e)

__device__ __forceinline__ float sigm_p(float y) {   // y pre-scaled: sigm = rcp(1+2^y)
    return __builtin_amdgcn_rcpf(1.0f + __builtin_amdgcn_exp2f(y));
}
__device__ __forceinline__ unsigned f2bf(float f) {
    unsigned u = __builtin_bit_cast(unsigned, f);
    u += 0x7fffu + ((u >> 16) & 1u);   // RNE
    return u >> 16;
}
__device__ __forceinline__ unsigned cvtpk(float lo, float hi) {
    unsigned r;
    asm("v_cvt_pk_bf16_f32 %0, %1, %2" : "=v"(r) : "v"(lo), "v"(hi));
    return r;
}

// prep: W_hh gate o (rows 384..511) -> PRESCALED bf16 B-fragments (32x32x16).
// dst[(ks*256 + gcol*2 + hf)*16] = W_o[gcol][ks*16+hf*8 .. +8] * NL2E
__global__ void prep_o(const float* __restrict__ W_hh, char* __restrict__ wso)
{
    int idx = blockIdx.x * 256 + threadIdx.x;   // 2048
    int ks = idx >> 8, gcol = (idx >> 1) & 127, hf = idx & 1;
    const float* src = W_hh + (size_t)(384 + gcol) * 128 + ks * 16 + hf * 8;
    float4 u = *(const float4*)src;
    float4 v = *(const float4*)(src + 4);
    U128 pk = { f2bf(u.x * NL2E) | (f2bf(u.y * NL2E) << 16),
                f2bf(u.z * NL2E) | (f2bf(u.w * NL2E) << 16),
                f2bf(v.x * NL2E) | (f2bf(v.y * NL2E) << 16),
                f2bf(v.z * NL2E) | (f2bf(v.w * NL2E) << 16) };
    *(U128*)(wso + (size_t)idx * 16) = pk;
}

__global__ __attribute__((amdgpu_waves_per_eu(2, 2))) __launch_bounds__(512)
void lstm_persist(const float* __restrict__ traj_in, const float* __restrict__ traj_gt,
                  const float* __restrict__ W_ih, const float* __restrict__ W_hh,
                  const float* __restrict__ b_ih, const float* __restrict__ b_hh,
                  const float* __restrict__ W_last, const float* __restrict__ b_last,
                  float* __restrict__ out, const char* __restrict__ wso,
                  float* __restrict__ wsloss)
{
    extern __shared__ char smem[];
    const int tid  = threadIdx.x;
    const int lane = tid & 63;
    const int wave = tid >> 6;          // 0..7
    const int l31  = lane & 31;
    const int half = lane >> 5;
    const int sw   = (l31 & 15) << 4;
    const int wm   = wave >> 2;         // rows wm*32..+31
    const int wc   = wave & 3;          // gate cols wc*32..+31
    const int col0 = wc * 32;
    const int myrow = wm * 32 + l31;
    const int rb0 = blockIdx.x * 128;   // group0 rows
    const int rb1 = rb0 + 64;           // group1 rows

    // ---- stage W_hh gates i,f,g -> LDS bf16, interleaved (col*3+gate)*256, PRESCALED
    for (int it = 0; it < 24; ++it) {
        int i = it * 512 + tid;            // 12288 float4 items, rows 0..383
        int n = i >> 5, c4 = i & 31;
        int gi = n >> 7, cn = n & 127;
        float sc = (gi == 2) ? N2L2E : NL2E;
        const float4 w = *(const float4*)(W_hh + (size_t)n * 128 + c4 * 4);
        uint2 pk = { f2bf(w.x * sc) | (f2bf(w.y * sc) << 16),
                     f2bf(w.z * sc) | (f2bf(w.w * sc) << 16) };
        *(uint2*)(smem + W_OFF + (cn * 3 + gi) * 256 + ((c4 * 8) ^ ((cn & 15) << 4))) = pk;
    }
    // ---- zero h0 and h1 (rh written at t=7 before first read at t=8)
    for (int i = 0; i < 16; ++i)
        *(unsigned*)(smem + H0_OFF + (tid + i * 512) * 4) = 0u;

    // ---- ext B-fragments (x-weights + bias), PRESCALED, 16 VGPRs
    short8 Ee[4];
    #pragma unroll
    for (int gg = 0; gg < 4; ++gg) {
        U128 v = { 0u, 0u, 0u, 0u };
        if (half == 0) {
            int n = gg * 128 + col0 + l31;
            float sc = (gg == 2) ? N2L2E : NL2E;
            float2 wi = *(const float2*)(W_ih + n * 2);
            float bsum = (b_ih[n] + b_hh[n]) * sc;
            v.a = f2bf(wi.x * sc) | (f2bf(wi.y * sc) << 16);
            v.b = f2bf(bsum);
        }
        Ee[gg] = __builtin_bit_cast(short8, v);
    }
    // ---- W_last A-fragments (lanes 0,1 = output rows), UNSCALED, 32 VGPRs
    short8 Wl[8];
    #pragma unroll
    for (int ks = 0; ks < 8; ++ks) {
        U128 q = { 0u, 0u, 0u, 0u };
        if (l31 < 2) {
            const float* p = W_last + l31 * 128 + ks * 16 + half * 8;
            float4 u = *(const float4*)p;
            float4 v = *(const float4*)(p + 4);
            q.a = f2bf(u.x) | (f2bf(u.y) << 16); q.b = f2bf(u.z) | (f2bf(u.w) << 16);
            q.c = f2bf(v.x) | (f2bf(v.y) << 16); q.d = f2bf(v.z) | (f2bf(v.w) << 16);
        }
        Wl[ks] = __builtin_bit_cast(short8, q);
    }
    const float bl0 = b_last[0], bl1 = b_last[1];

    // ---- step-invariant read addresses (kept in registers)
    int aAddr[8], wAddr[8];
    #pragma unroll
    for (int ks = 0; ks < 8; ++ks) {
        const int bv = (ks * 32 + half * 16) ^ sw;
        aAddr[ks] = H0_OFF + myrow * 256 + bv;            // +16384 for h1; +32768 for rh0; +49152 rh1
        wAddr[ks] = W_OFF + (col0 + l31) * 768 + bv;
    }
    // h-write base: addr = hwBase + Kr (compile-time) + baddr(r)
    const int hwBase = H0_OFF + wm * 8192 + (half << 10);
    const int cbase  = (col0 + l31) * 2;
    const int hh6    = half << 6;
    const char* woB  = wso + (size_t)((col0 + l31) * 2 + half) * 16;

    f32x16 zacc{};     // persistent zero C-operand
    float lossAcc = 0.f;

    __syncthreads();

    float c0_[16], c1_[16];
    #pragma unroll
    for (int r = 0; r < 16; ++r) { c0_[r] = 0.f; c1_[r] = 0.f; }

    for (int t = 0; t < NCELL; ++t) {
        // ================= phase A: all reads of h/rh state =================
        float2 xx0 = make_float2(0.f, 0.f), xx1 = xx0;
        if (t < OBS) {
            if (half == 0) {
                xx0 = *(const float2*)(traj_in + ((size_t)(rb0 + myrow) * OBS + t) * 2);
                xx1 = *(const float2*)(traj_in + ((size_t)(rb1 + myrow) * OBS + t) * 2);
            }
        } else {
            f32x16 hd0, hd1;
            {
                short8 q0 = *(const short8*)(smem + aAddr[0] + 32768);
                short8 q1 = *(const short8*)(smem + aAddr[0] + 49152);
                hd0 = __builtin_amdgcn_mfma_f32_32x32x16_bf16(Wl[0], q0, zacc, 0, 0, 0);
                hd1 = __builtin_amdgcn_mfma_f32_32x32x16_bf16(Wl[0], q1, zacc, 0, 0, 0);
            }
            #pragma unroll
            for (int ks = 1; ks < 8; ++ks) {
                short8 q0 = *(const short8*)(smem + aAddr[ks] + 32768);
                short8 q1 = *(const short8*)(smem + aAddr[ks] + 49152);
                hd0 = __builtin_amdgcn_mfma_f32_32x32x16_bf16(Wl[ks], q0, hd0, 0, 0, 0);
                hd1 = __builtin_amdgcn_mfma_f32_32x32x16_bf16(Wl[ks], q1, hd1, 0, 0, 0);
            }
            if (half == 0) {
                xx0.x = hd0[0] + bl0;  xx0.y = hd0[1] + bl1;
                xx1.x = hd1[0] + bl0;  xx1.y = hd1[1] + bl1;
                if (wc == 0) {         // emit p = t-8 for both groups
                    size_t og0 = ((size_t)(rb0 + myrow) * PREDL + (t - OBS)) * 2;
                    size_t og1 = ((size_t)(rb1 + myrow) * PREDL + (t - OBS)) * 2;
                    float2 g0 = *(const float2*)(traj_gt + og0);
                    float2 g1 = *(const float2*)(traj_gt + og1);
                    *(float2*)(out + og0) = xx0;
                    *(float2*)(out + og1) = xx1;
                    float d0 = xx0.x - g0.x, d1 = xx0.y - g0.y;
                    float d2 = xx1.x - g1.x, d3 = xx1.y - g1.y;
                    lossAcc = fmaf(d0, d0, fmaf(d1, d1, fmaf(d2, d2, fmaf(d3, d3, lossAcc))));
                }
            }
        }
        short8 a0[8], a1[8];
        #pragma unroll
        for (int ks = 0; ks < 8; ++ks) {
            a0[ks] = *(const short8*)(smem + aAddr[ks]);
            a1[ks] = *(const short8*)(smem + aAddr[ks] + 16384);
        }
        __syncthreads();   // B1: all h/rh reads complete

        const bool doRelu = (t >= OBS - 1);

        // ================= phase B: compute + writes, group1 first =================
        #pragma unroll
        for (int g = 0; g < 2; ++g) {
            // g==0 processes group1 (frees a1 first), g==1 processes group0
            f32x16 ac0, ac1, ac2, ac3;
            {
                short8 af = g ? a0[0] : a1[0];
                const char* wb = smem + wAddr[0];
                short8 bo = *(const short8*)(woB);
                ac0 = __builtin_amdgcn_mfma_f32_32x32x16_bf16(af, *(const short8*)(wb),       zacc, 0, 0, 0);
                ac1 = __builtin_amdgcn_mfma_f32_32x32x16_bf16(af, *(const short8*)(wb + 256), zacc, 0, 0, 0);
                ac2 = __builtin_amdgcn_mfma_f32_32x32x16_bf16(af, *(const short8*)(wb + 512), zacc, 0, 0, 0);
                ac3 = __builtin_amdgcn_mfma_f32_32x32x16_bf16(af, bo,                         zacc, 0, 0, 0);
            }
            #pragma unroll
            for (int ks = 1; ks < 8; ++ks) {
                short8 af = g ? a0[ks] : a1[ks];
                const char* wb = smem + wAddr[ks];
                short8 bo = *(const short8*)(woB + ks * 4096);
                ac0 = __builtin_amdgcn_mfma_f32_32x32x16_bf16(af, *(const short8*)(wb),       ac0, 0, 0, 0);
                ac1 = __builtin_amdgcn_mfma_f32_32x32x16_bf16(af, *(const short8*)(wb + 256), ac1, 0, 0, 0);
                ac2 = __builtin_amdgcn_mfma_f32_32x32x16_bf16(af, *(const short8*)(wb + 512), ac2, 0, 0, 0);
                ac3 = __builtin_amdgcn_mfma_f32_32x32x16_bf16(af, bo,                         ac3, 0, 0, 0);
            }
            {   // K-extension slice last: x * W_ih^T + bias (prescaled)
                float2 xx = g ? xx0 : xx1;
                unsigned xv = (half == 0) ? cvtpk(xx.x, xx.y) : 0u;
                U128 ax = { xv, (half == 0) ? 0x00003F80u : 0u, 0u, 0u };
                short8 aext = __builtin_bit_cast(short8, ax);
                ac0 = __builtin_amdgcn_mfma_f32_32x32x16_bf16(aext, Ee[0], ac0, 0, 0, 0);
                ac1 = __builtin_amdgcn_mfma_f32_32x32x16_bf16(aext, Ee[1], ac1, 0, 0, 0);
                ac2 = __builtin_amdgcn_mfma_f32_32x32x16_bf16(aext, Ee[2], ac2, 0, 0, 0);
                ac3 = __builtin_amdgcn_mfma_f32_32x32x16_bf16(aext, Ee[3], ac3, 0, 0, 0);
            }

            float* cc = g ? c0_ : c1_;
            const int gOff = g ? 0 : 16384;       // h0 vs h1 region
            #pragma unroll
            for (int r = 0; r < 16; ++r) {
                float iv = sigm_p(ac0[r]);
                float fv = sigm_p(ac1[r]);
                float gv = fmaf(2.f, sigm_p(ac2[r]), -1.f);
                float ov = sigm_p(ac3[r]);
                float cv = fmaf(fv, cc[r], iv * gv);
                cc[r] = cv;
                float th = fmaf(2.f, sigm_p(cv * N2L2E), -1.f);
                float hv = ov * th;
                float rl = fmaxf(hv, 0.f);
                unsigned hp = cvtpk(hv, rl);       // low = h, high = relu(h)
                // addr = hwBase + gOff + Kr + (cbase ^ (Krb | hh6)); Kr,Krb compile-time
                const int Kr  = ((r & 3) << 8) + ((r >> 2) << 11);
                const int Krb = ((r & 3) << 4) + (((r >> 2) & 1) << 7);
                const int baddr = cbase ^ (Krb | hh6);
                char* wp = smem + hwBase + gOff + Kr + baddr;
                *(short*)(wp) = (short)hp;
                if (doRelu)
                    *(short*)(wp + 32768) = (short)(hp >> 16);
            }
        }
        __syncthreads();   // B2: h/rh writes visible for t+1 phase A
    }

    // ---- tail: p = 11 = head(h_18) for both groups
    if (wc == 0) {
        f32x16 hd0, hd1;
        {
            short8 q0 = *(const short8*)(smem + aAddr[0] + 32768);
            short8 q1 = *(const short8*)(smem + aAddr[0] + 49152);
            hd0 = __builtin_amdgcn_mfma_f32_32x32x16_bf16(Wl[0], q0, zacc, 0, 0, 0);
            hd1 = __builtin_amdgcn_mfma_f32_32x32x16_bf16(Wl[0], q1, zacc, 0, 0, 0);
        }
        #pragma unroll
        for (int ks = 1; ks < 8; ++ks) {
            short8 q0 = *(const short8*)(smem + aAddr[ks] + 32768);
            short8 q1 = *(const short8*)(smem + aAddr[ks] + 49152);
            hd0 = __builtin_amdgcn_mfma_f32_32x32x16_bf16(Wl[ks], q0, hd0, 0, 0, 0);
            hd1 = __builtin_amdgcn_mfma_f32_32x32x16_bf16(Wl[ks], q1, hd1, 0, 0, 0);
        }
        if (half == 0) {
            size_t og0 = ((size_t)(rb0 + myrow) * PREDL + (PREDL - 1)) * 2;
            size_t og1 = ((size_t)(rb1 + myrow) * PREDL + (PREDL - 1)) * 2;
            float o0 = hd0[0] + bl0, o1 = hd0[1] + bl1;
            float o2 = hd1[0] + bl0, o3 = hd1[1] + bl1;
            float2 g0 = *(const float2*)(traj_gt + og0);
            float2 g1 = *(const float2*)(traj_gt + og1);
            *(float2*)(out + og0) = make_float2(o0, o1);
            *(float2*)(out + og1) = make_float2(o2, o3);
            float d0 = o0 - g0.x, d1 = o1 - g0.y;
            float d2 = o2 - g1.x, d3 = o3 - g1.y;
            lossAcc = fmaf(d0, d0, fmaf(d1, d1, fmaf(d2, d2, fmaf(d3, d3, lossAcc))));
        }
    }

    // ---- block loss partial (deterministic; reuse rh0 region as scratch)
    #pragma unroll
    for (int s = 1; s < 64; s <<= 1) lossAcc += __shfl_xor(lossAcc, s, 64);
    __syncthreads();
    float* sred = (float*)(smem + RH0_OFF);
    if (lane == 0) sred[wave] = lossAcc;
    __syncthreads();
    if (tid == 0) {
        float s = 0.f;
        #pragma unroll
        for (int i = 0; i < 8; ++i) s += sred[i];
        wsloss[blockIdx.x] = s;
    }
}

__global__ void loss_reduce(const float* __restrict__ wsloss, float* __restrict__ out,
                            int npart, int nelem)
{
    __shared__ float sacc[4];
    int tid = threadIdx.x;   // 256
    float v = 0.f;
    for (int j = tid; j < npart; j += 256) v += wsloss[j];   // fixed order per lane
    #pragma unroll
    for (int s = 1; s < 64; s <<= 1) v += __shfl_xor(v, s, 64);
    if ((tid & 63) == 0) sacc[tid >> 6] = v;
    __syncthreads();
    if (tid == 0) out[nelem] = (sacc[0] + sacc[1] + sacc[2] + sacc[3]) / (float)nelem;
}

extern "C" void kernel_launch(void* const* d_in, const int* in_sizes, int n_in,
                              void* d_out, int out_size, void* d_ws, size_t ws_size,
                              hipStream_t stream)
{
    const float* traj_in = (const float*)d_in[0];
    const float* traj_gt = (const float*)d_in[1];
    const float* W_ih    = (const float*)d_in[2];
    const float* W_hh    = (const float*)d_in[3];
    const float* b_ih    = (const float*)d_in[4];
    const float* b_hh    = (const float*)d_in[5];
    const float* W_last  = (const float*)d_in[6];
    const float* b_last  = (const float*)d_in[7];
    float* out = (float*)d_out;
    char*  wso    = (char*)d_ws;                      // 32 KB prescaled gate-o fragments
    float* wsloss = (float*)((char*)d_ws + 32768);

    const int B      = in_sizes[0] / (OBS * 2);   // 32768
    const int blocks = B / 128;                    // 256 (two 64-row groups interleaved)

    prep_o<<<8, 256, 0, stream>>>(W_hh, wso);
    lstm_persist<<<blocks, 512, LDS_BYTES, stream>>>(traj_in, traj_gt, W_ih, W_hh,
                                                     b_ih, b_hh, W_last, b_last,
                                                     out, wso, wsloss);
    loss_reduce<<<1, 256, 0, stream>>>(wsloss, out, blocks, out_size - 1);
}

// Round 18
// 151.648 us; speedup vs baseline: 3.6793x; 3.6793x over previous
//
#include <hip/hip_runtime.h>

#define OBS 8
#define PREDL 12
#define NCELL 19   // cell evals t=0..18; x_t=head(h_t) for t>=8; emit p=t-8; p=11 in tail

// LDS map (bytes)
#define W_OFF    0        // 98304: W_hh i,f,g interleaved (gcol*3+gate)*256, swizzled(&15), prescaled
#define H_OFF    98304    // 16384: h single buffer, 64 rows x 256B, swizzled(&15)
#define RH_OFF   114688   // 16384: relu(h) single buffer
#define EE_OFF   131072   // 8192: ext fragments [512][16B] = {wih0*sc, wih1*sc, bias*sc, 0..}
#define EEZ_OFF  139264   // 16: zero block
#define WL_OFF   139280   // 4096: W_last as A-fragments: 16 rows x 256B swizzled (rows 2..15 zero)
#define RED_OFF  143376   // 64: loss partials
#define LDS_BYTES 143440

typedef short short8 __attribute__((ext_vector_type(8)));
typedef float f32x4  __attribute__((ext_vector_type(4)));
struct U128 { unsigned a, b, c, d; };

#define NL2E  (-1.4426950408889634f)
#define N2L2E (-2.8853900817779268f)

__device__ __forceinline__ float sigm_p(float y) {   // pre-scaled: sigm = rcp(1+2^y)
    return __builtin_amdgcn_rcpf(1.0f + __builtin_amdgcn_exp2f(y));
}
__device__ __forceinline__ unsigned f2bf(float f) {
    unsigned u = __builtin_bit_cast(unsigned, f);
    u += 0x7fffu + ((u >> 16) & 1u);   // RNE
    return u >> 16;
}
__device__ __forceinline__ unsigned cvtpk(float lo, float hi) {
    unsigned r;
    asm("v_cvt_pk_bf16_f32 %0, %1, %2" : "=v"(r) : "v"(lo), "v"(hi));
    return r;
}

// prep: W_hh gate o (rows 384..511) -> PRESCALED bf16 16x16x32-B fragments.
// dst[((ks*128 + gcol)*4 + q)*16] = W_o[gcol][ks*32+q*8 .. +8] * NL2E
__global__ void prep_o(const float* __restrict__ W_hh, char* __restrict__ wso)
{
    int idx = blockIdx.x * 256 + threadIdx.x;   // 2048
    int ks = idx >> 9, rest = idx & 511;
    int gcol = rest >> 2, q = rest & 3;
    const float* src = W_hh + (size_t)(384 + gcol) * 128 + ks * 32 + q * 8;
    float4 u = *(const float4*)src;
    float4 v = *(const float4*)(src + 4);
    U128 pk = { f2bf(u.x * NL2E) | (f2bf(u.y * NL2E) << 16),
                f2bf(u.z * NL2E) | (f2bf(u.w * NL2E) << 16),
                f2bf(v.x * NL2E) | (f2bf(v.y * NL2E) << 16),
                f2bf(v.z * NL2E) | (f2bf(v.w * NL2E) << 16) };
    *(U128*)(wso + (size_t)idx * 16) = pk;
}

__global__ __attribute__((amdgpu_waves_per_eu(4, 4))) __launch_bounds__(1024)
void lstm_persist(const float* __restrict__ traj_in, const float* __restrict__ traj_gt,
                  const float* __restrict__ W_ih, const float* __restrict__ W_hh,
                  const float* __restrict__ b_ih, const float* __restrict__ b_hh,
                  const float* __restrict__ W_last, const float* __restrict__ b_last,
                  float* __restrict__ out, const char* __restrict__ wso,
                  float* __restrict__ wsloss)
{
    extern __shared__ char smem[];
    const int tid  = threadIdx.x;
    const int lane = tid & 63;
    const int wave = tid >> 6;          // 0..15
    const int l15  = lane & 15;
    const int q    = lane >> 4;         // 0..3
    const int rg   = wave >> 2;         // rows rg*16..+15
    const int cg   = wave & 3;          // hcols cg*32..+31 (2 tiles of 16)
    const int rowb = rg * 16 + l15;     // batch row (A/B col role)

    // ---- stage W_hh i,f,g -> LDS, interleaved, prescaled, swizzled(&15)
    for (int it = 0; it < 12; ++it) {
        int i = it * 1024 + tid;           // 12288 float4 items, rows 0..383
        int n = i >> 5, c4 = i & 31;
        int gi = n >> 7, cn = n & 127;
        float sc = (gi == 2) ? N2L2E : NL2E;
        const float4 w = *(const float4*)(W_hh + (size_t)n * 128 + c4 * 4);
        uint2 pk = { f2bf(w.x * sc) | (f2bf(w.y * sc) << 16),
                     f2bf(w.z * sc) | (f2bf(w.w * sc) << 16) };
        *(uint2*)(smem + W_OFF + (cn * 3 + gi) * 256 + ((c4 * 8) ^ ((cn & 15) << 4))) = pk;
    }
    // ---- stage EE: row n = {wih0*sc, wih1*sc, bias*sc, 0 x5} bf16
    if (tid < 512) {
        int n = tid, gg = n >> 7;
        float sc = (gg == 2) ? N2L2E : NL2E;
        float2 wi = *(const float2*)(W_ih + n * 2);
        float bsum = (b_ih[n] + b_hh[n]) * sc;
        U128 pk = { f2bf(wi.x * sc) | (f2bf(wi.y * sc) << 16), f2bf(bsum), 0u, 0u };
        *(U128*)(smem + EE_OFF + n * 16) = pk;
    }
    // ---- WL: zero rows 2..15 (3584B), then write rows 0,1 (512B, disjoint)
    if (tid < 896) *(unsigned*)(smem + WL_OFF + 512 + tid * 4) = 0u;
    if (tid < 256) {
        int row = tid >> 7, k = tid & 127;
        *(unsigned short*)(smem + WL_OFF + row * 256 + ((k * 2) ^ ((row & 15) << 4))) =
            (unsigned short)f2bf(W_last[tid]);
    }
    if (tid >= 1020) *(unsigned*)(smem + EEZ_OFF + (tid - 1020) * 4) = 0u;

    const float bl0 = b_last[0], bl1 = b_last[1];

    // ---- step-invariant addresses
    int koff[4];
    #pragma unroll
    for (int ks = 0; ks < 4; ++ks)
        koff[ks] = (ks * 64 + q * 16) ^ (l15 << 4);
    const int aBase  = H_OFF + rowb * 256;      // + koff[ks]; +16384 for rh
    const int wlBase = WL_OFF + l15 * 256;      // + koff[ks]
    const int gcol0 = cg * 32 + l15, gcol1 = gcol0 + 16;
    const int gB0 = W_OFF + gcol0 * 768, gB1 = W_OFF + gcol1 * 768;
    const int oB0 = gcol0 * 64 + q * 16, oB1 = gcol1 * 64 + q * 16;   // + ks*8192
    const int eStep = (q == 0) ? 2048 : 0;
    const int eB0 = (q == 0) ? (EE_OFF + gcol0 * 16) : EEZ_OFF;
    const int eB1 = (q == 0) ? (EE_OFF + gcol1 * 16) : EEZ_OFF;
    int hwA[2][4];
    #pragma unroll
    for (int t2 = 0; t2 < 2; ++t2)
        #pragma unroll
        for (int r = 0; r < 4; ++r) {
            const int row = q * 4 + r;
            hwA[t2][r] = H_OFF + (rg * 16 + row) * 256 +
                         (((cg * 32 + t2 * 16 + l15) * 2) ^ ((row & 15) << 4));
        }

    f32x4 zacc{};
    float lossAcc = 0.f;

    for (int g = 0; g < 2; ++g) {
        const int rbase = blockIdx.x * 128 + g * 64;

        __syncthreads();
        for (int i = 0; i < 4; ++i)
            *(unsigned*)(smem + H_OFF + (tid + i * 1024) * 4) = 0u;
        __syncthreads();

        float c_[8];
        #pragma unroll
        for (int i = 0; i < 8; ++i) c_[i] = 0.f;

        for (int t = 0; t < NCELL; ++t) {
            // ---- x: obs from global; pred via head-MFMA on rh (lands in q==0 lanes)
            float2 xx = make_float2(0.f, 0.f);
            if (t < OBS) {
                if (q == 0)
                    xx = *(const float2*)(traj_in + ((size_t)(rbase + rowb) * OBS + t) * 2);
            } else {
                f32x4 hd = zacc;
                #pragma unroll
                for (int ks = 0; ks < 4; ++ks) {
                    short8 wl = *(const short8*)(smem + wlBase + koff[ks]);
                    short8 rb = *(const short8*)(smem + aBase + 16384 + koff[ks]);
                    hd = __builtin_amdgcn_mfma_f32_16x16x32_bf16(wl, rb, hd, 0, 0, 0);
                }
                if (q == 0) {
                    xx.x = hd[0] + bl0;   // D row0 -> q=0,r=0 ; col=l15=batch row
                    xx.y = hd[1] + bl1;
                    if (cg == 0) {        // emit p = t-8
                        size_t og = ((size_t)(rbase + rowb) * PREDL + (t - OBS)) * 2;
                        float2 gt = *(const float2*)(traj_gt + og);
                        *(float2*)(out + og) = xx;
                        float d0 = xx.x - gt.x, d1 = xx.y - gt.y;
                        lossAcc = fmaf(d0, d0, fmaf(d1, d1, lossAcc));
                    }
                }
            }

            // ---- A fragments from h
            short8 a[4];
            #pragma unroll
            for (int ks = 0; ks < 4; ++ks)
                a[ks] = *(const short8*)(smem + aBase + koff[ks]);

            // ---- gates: K=128 (i,f,g LDS; o streamed), ext last
            f32x4 ac[4][2];
            #pragma unroll
            for (int ks = 0; ks < 4; ++ks) {
                const char* w0 = smem + gB0 + koff[ks];
                const char* w1 = smem + gB1 + koff[ks];
                short8 bo0 = *(const short8*)(wso + ks * 8192 + oB0);
                short8 bo1 = *(const short8*)(wso + ks * 8192 + oB1);
                if (ks == 0) {
                    ac[0][0] = __builtin_amdgcn_mfma_f32_16x16x32_bf16(a[0], *(const short8*)(w0),       zacc, 0, 0, 0);
                    ac[0][1] = __builtin_amdgcn_mfma_f32_16x16x32_bf16(a[0], *(const short8*)(w1),       zacc, 0, 0, 0);
                    ac[1][0] = __builtin_amdgcn_mfma_f32_16x16x32_bf16(a[0], *(const short8*)(w0 + 256), zacc, 0, 0, 0);
                    ac[1][1] = __builtin_amdgcn_mfma_f32_16x16x32_bf16(a[0], *(const short8*)(w1 + 256), zacc, 0, 0, 0);
                    ac[2][0] = __builtin_amdgcn_mfma_f32_16x16x32_bf16(a[0], *(const short8*)(w0 + 512), zacc, 0, 0, 0);
                    ac[2][1] = __builtin_amdgcn_mfma_f32_16x16x32_bf16(a[0], *(const short8*)(w1 + 512), zacc, 0, 0, 0);
                    ac[3][0] = __builtin_amdgcn_mfma_f32_16x16x32_bf16(a[0], bo0,                        zacc, 0, 0, 0);
                    ac[3][1] = __builtin_amdgcn_mfma_f32_16x16x32_bf16(a[0], bo1,                        zacc, 0, 0, 0);
                } else {
                    ac[0][0] = __builtin_amdgcn_mfma_f32_16x16x32_bf16(a[ks], *(const short8*)(w0),       ac[0][0], 0, 0, 0);
                    ac[0][1] = __builtin_amdgcn_mfma_f32_16x16x32_bf16(a[ks], *(const short8*)(w1),       ac[0][1], 0, 0, 0);
                    ac[1][0] = __builtin_amdgcn_mfma_f32_16x16x32_bf16(a[ks], *(const short8*)(w0 + 256), ac[1][0], 0, 0, 0);
                    ac[1][1] = __builtin_amdgcn_mfma_f32_16x16x32_bf16(a[ks], *(const short8*)(w1 + 256), ac[1][1], 0, 0, 0);
                    ac[2][0] = __builtin_amdgcn_mfma_f32_16x16x32_bf16(a[ks], *(const short8*)(w0 + 512), ac[2][0], 0, 0, 0);
                    ac[2][1] = __builtin_amdgcn_mfma_f32_16x16x32_bf16(a[ks], *(const short8*)(w1 + 512), ac[2][1], 0, 0, 0);
                    ac[3][0] = __builtin_amdgcn_mfma_f32_16x16x32_bf16(a[ks], bo0,                        ac[3][0], 0, 0, 0);
                    ac[3][1] = __builtin_amdgcn_mfma_f32_16x16x32_bf16(a[ks], bo1,                        ac[3][1], 0, 0, 0);
                }
            }
            {   // ext last: x*W_ih + bias (prescaled)
                unsigned xv = (q == 0) ? cvtpk(xx.x, xx.y) : 0u;
                U128 ax = { xv, (q == 0) ? 0x00003F80u : 0u, 0u, 0u };
                short8 aext = __builtin_bit_cast(short8, ax);
                #pragma unroll
                for (int gg = 0; gg < 4; ++gg) {
                    short8 e0 = *(const short8*)(smem + eB0 + gg * eStep);
                    short8 e1 = *(const short8*)(smem + eB1 + gg * eStep);
                    ac[gg][0] = __builtin_amdgcn_mfma_f32_16x16x32_bf16(aext, e0, ac[gg][0], 0, 0, 0);
                    ac[gg][1] = __builtin_amdgcn_mfma_f32_16x16x32_bf16(aext, e1, ac[gg][1], 0, 0, 0);
                }
            }

            // ---- elementwise -> hp registers
            unsigned hp[2][4];
            const bool doRelu = (t >= OBS - 1);
            #pragma unroll
            for (int t2 = 0; t2 < 2; ++t2)
                #pragma unroll
                for (int r = 0; r < 4; ++r) {
                    float iv = sigm_p(ac[0][t2][r]);
                    float fv = sigm_p(ac[1][t2][r]);
                    float gv = fmaf(2.f, sigm_p(ac[2][t2][r]), -1.f);
                    float ov = sigm_p(ac[3][t2][r]);
                    float cv = fmaf(fv, c_[t2 * 4 + r], iv * gv);
                    c_[t2 * 4 + r] = cv;
                    float th = fmaf(2.f, sigm_p(cv * N2L2E), -1.f);
                    float hv = ov * th;
                    hp[t2][r] = cvtpk(hv, fmaxf(hv, 0.f));
                }

            __syncthreads();   // B1: all reads of h/rh complete
            #pragma unroll
            for (int t2 = 0; t2 < 2; ++t2)
                #pragma unroll
                for (int r = 0; r < 4; ++r) {
                    *(unsigned short*)(smem + hwA[t2][r]) = (unsigned short)hp[t2][r];
                    if (doRelu)
                        *(unsigned short*)(smem + hwA[t2][r] + 16384) = (unsigned short)(hp[t2][r] >> 16);
                }
            __syncthreads();   // B2: writes visible for next step
        }

        // ---- tail: p = 11 = head(h_19) on final rh
        if (cg == 0) {
            f32x4 hd = zacc;
            #pragma unroll
            for (int ks = 0; ks < 4; ++ks) {
                short8 wl = *(const short8*)(smem + wlBase + koff[ks]);
                short8 rb = *(const short8*)(smem + aBase + 16384 + koff[ks]);
                hd = __builtin_amdgcn_mfma_f32_16x16x32_bf16(wl, rb, hd, 0, 0, 0);
            }
            if (q == 0) {
                float o0 = hd[0] + bl0, o1 = hd[1] + bl1;
                size_t og = ((size_t)(rbase + rowb) * PREDL + (PREDL - 1)) * 2;
                float2 gt = *(const float2*)(traj_gt + og);
                *(float2*)(out + og) = make_float2(o0, o1);
                float d0 = o0 - gt.x, d1 = o1 - gt.y;
                lossAcc = fmaf(d0, d0, fmaf(d1, d1, lossAcc));
            }
        }
    }

    // ---- block loss partial (deterministic)
    #pragma unroll
    for (int s = 1; s < 64; s <<= 1) lossAcc += __shfl_xor(lossAcc, s, 64);
    __syncthreads();
    float* sred = (float*)(smem + RED_OFF);
    if (lane == 0) sred[wave] = lossAcc;
    __syncthreads();
    if (tid == 0) {
        float s = 0.f;
        #pragma unroll
        for (int i = 0; i < 16; ++i) s += sred[i];
        wsloss[blockIdx.x] = s;
    }
}

__global__ void loss_reduce(const float* __restrict__ wsloss, float* __restrict__ out,
                            int npart, int nelem)
{
    __shared__ float sacc[4];
    int tid = threadIdx.x;   // 256
    float v = 0.f;
    for (int j = tid; j < npart; j += 256) v += wsloss[j];
    #pragma unroll
    for (int s = 1; s < 64; s <<= 1) v += __shfl_xor(v, s, 64);
    if ((tid & 63) == 0) sacc[tid >> 6] = v;
    __syncthreads();
    if (tid == 0) out[nelem] = (sacc[0] + sacc[1] + sacc[2] + sacc[3]) / (float)nelem;
}

extern "C" void kernel_launch(void* const* d_in, const int* in_sizes, int n_in,
                              void* d_out, int out_size, void* d_ws, size_t ws_size,
                              hipStream_t stream)
{
    const float* traj_in = (const float*)d_in[0];
    const float* traj_gt = (const float*)d_in[1];
    const float* W_ih    = (const float*)d_in[2];
    const float* W_hh    = (const float*)d_in[3];
    const float* b_ih    = (const float*)d_in[4];
    const float* b_hh    = (const float*)d_in[5];
    const float* W_last  = (const float*)d_in[6];
    const float* b_last  = (const float*)d_in[7];
    float* out = (float*)d_out;
    char*  wso    = (char*)d_ws;                      // 32 KB prescaled gate-o fragments
    float* wsloss = (float*)((char*)d_ws + 32768);

    const int B      = in_sizes[0] / (OBS * 2);   // 32768
    const int blocks = B / 128;                    // 256 (two 64-row groups, g-loop)

    prep_o<<<8, 256, 0, stream>>>(W_hh, wso);
    lstm_persist<<<blocks, 1024, LDS_BYTES, stream>>>(traj_in, traj_gt, W_ih, W_hh,
                                                      b_ih, b_hh, W_last, b_last,
                                                      out, wso, wsloss);
    loss_reduce<<<1, 256, 0, stream>>>(wsloss, out, blocks, out_size - 1);
}